// Round 21
// baseline (82.978 us; speedup 1.0000x reference)
//
#include <hip/hip_runtime.h>

#define N_NODES 100000
#define N_EDGES 1600000
#define IN_DIM 256
#define OUT_DIM 32

#define SB_SHIFT 7                          // bucket = node >> 7 (128 nodes)
#define NSB ((N_NODES + 127) >> 7)          // 782
#define SBCAP 2368                          // mean 2046 + ~7 sigma
#define EBLK 2048                           // edges per part1 block
#define NB1 ((N_EDGES + EBLK - 1) / EBLK)   // 782
#define NGB ((N_NODES + 255) / 256)         // 391 gemm blocks

typedef __attribute__((ext_vector_type(8))) short short8;
typedef __attribute__((ext_vector_type(16))) float f32x16;

#define WT_STRIDE 264    // 256 + 8 pad (bf16 elems)

__device__ inline unsigned short f2bf(float f) {
    unsigned u = __float_as_uint(f);
    unsigned r = u + 0x7FFF + ((u >> 16) & 1);   // round-to-nearest-even
    return (unsigned short)(r >> 16);
}
__device__ inline float bf2f(unsigned short us) {
    return __uint_as_float((unsigned)us << 16);
}

// ---------------------------------------------------------------------------
// K1 mega (R21): same structure as R14/R18 (measured best). Changes:
//  - __launch_bounds__(512, 8): permit 64 VGPR at unchanged 8 waves/SIMD
//    (R20 compiled to VGPR=32 -> only ~2 x-loads in flight per lane).
//  - gemm branch: 4-slot rotating load buffer, fully unrolled (static
//    indices) -> 8 float4 loads in flight steady-state.
// part1 branch byte-identical.
// ---------------------------------------------------------------------------
__global__ __launch_bounds__(512, 8) void k_mega(const int* __restrict__ src,
                                              const int* __restrict__ dst,
                                              unsigned long long* __restrict__ qcnt,
                                              unsigned* __restrict__ gsb,
                                              unsigned char* __restrict__ gss,
                                              const float* __restrict__ x,
                                              const float* __restrict__ W,
                                              unsigned short* __restrict__ h2) {
    __shared__ __align__(16) int smemI[6 * NSB + 2 * EBLK];   // 35152 B
    const int tid = threadIdx.x;
    const int bid = blockIdx.x;
    const int g = bid / 3;
    const int rem = bid - g * 3;

    if (rem == 0) {
        // ---------------- GEMM branch: rows [g*256, g*256+256) ----
        unsigned short* WT = (unsigned short*)smemI;   // 16896 B
        #pragma unroll
        for (int i = 0; i < 16; ++i) {
            int idx = tid + i * 512;        // k = idx>>5, c = idx&31
            WT[(idx & 31) * WT_STRIDE + (idx >> 5)] = f2bf(W[idx]);
        }
        __syncthreads();

        const int wv = tid >> 6;
        const int lane = tid & 63;
        const int col = lane & 31;
        const int hi = lane >> 5;

        const int row0 = g * 256 + wv * 32;
        int grow = row0 + col;
        int growc = grow < N_NODES ? grow : N_NODES - 1;
        const float4* xrow = reinterpret_cast<const float4*>(x + (size_t)growc * IN_DIM);

        f32x16 acc = {0.f,0.f,0.f,0.f,0.f,0.f,0.f,0.f,
                      0.f,0.f,0.f,0.f,0.f,0.f,0.f,0.f};

        // prologue: fill 4 slots (8 loads in flight)
        float4 p0[4], p1[4];
        #pragma unroll
        for (int t = 0; t < 4; ++t) {
            p0[t] = xrow[t * 4 + hi * 2];
            p1[t] = xrow[t * 4 + hi * 2 + 1];
        }

        #pragma unroll
        for (int t = 0; t < 16; ++t) {
            const int sl = t & 3;
            float4 q0 = p0[sl];
            float4 q1 = p1[sl];
            if (t + 4 < 16) {               // refill slot 4 ahead
                p0[sl] = xrow[(t + 4) * 4 + hi * 2];
                p1[sl] = xrow[(t + 4) * 4 + hi * 2 + 1];
            }
            short8 a;
            a[0] = (short)f2bf(q0.x); a[1] = (short)f2bf(q0.y);
            a[2] = (short)f2bf(q0.z); a[3] = (short)f2bf(q0.w);
            a[4] = (short)f2bf(q1.x); a[5] = (short)f2bf(q1.y);
            a[6] = (short)f2bf(q1.z); a[7] = (short)f2bf(q1.w);
            short8 bfr = *reinterpret_cast<const short8*>(
                &WT[col * WT_STRIDE + t * 16 + hi * 8]);
            acc = __builtin_amdgcn_mfma_f32_32x32x16_bf16(a, bfr, acc, 0, 0, 0);
        }

        #pragma unroll
        for (int r = 0; r < 16; ++r) {
            int rowi = (r & 3) + 8 * (r >> 2) + 4 * hi;
            int go = row0 + rowi;
            if (go < N_NODES)
                h2[(size_t)go * OUT_DIM + col] = f2bf(acc[r]);   // norm deferred
        }
    } else {
        // ---------------- part1 branch: 782 buckets of 128 nodes ----
        const int pb = 2 * g + rem - 1;     // 0..781
        int* hist    = smemI;
        int* bbase   = smemI + NSB;
        int* cur     = smemI + 2 * NSB;
        int* hist_s  = smemI + 3 * NSB;
        int* bbase_s = smemI + 4 * NSB;
        int* cur_s   = smemI + 5 * NSB;
        int* es      = smemI + 6 * NSB;
        int* ed      = smemI + 6 * NSB + EBLK;

        const int e0 = pb * EBLK;
        const int n = min(EBLK, N_EDGES - e0);

        for (int i = tid; i < NSB; i += 512) {
            hist[i] = 0; cur[i] = 0; hist_s[i] = 0; cur_s[i] = 0;
        }
        __syncthreads();

        for (int i = tid; i < n; i += 512) {
            int s = src[e0 + i];
            int d = dst[e0 + i];
            es[i] = s; ed[i] = d;
            atomicAdd(&hist[d >> SB_SHIFT], 1);
            atomicAdd(&hist_s[s >> SB_SHIFT], 1);
        }
        __syncthreads();

        for (int i = tid; i < NSB; i += 512) {
            unsigned long long pack =
                ((unsigned long long)(unsigned)hist_s[i] << 32) | (unsigned)hist[i];
            unsigned long long old = atomicAdd(&qcnt[i], pack);
            bbase[i]   = (int)(old & 0xFFFFFFFFull);
            bbase_s[i] = (int)(old >> 32);
        }
        __syncthreads();

        for (int i = tid; i < n; i += 512) {
            int d = ed[i];
            int s = es[i];
            int r = d >> SB_SHIFT;
            int lp = atomicAdd(&cur[r], 1);
            int pos = bbase[r] + lp;
            if (pos < SBCAP)
                gsb[(size_t)r * SBCAP + pos] = ((unsigned)(d & 127) << 17) | (unsigned)s;
            int rs = s >> SB_SHIFT;
            int lp2 = atomicAdd(&cur_s[rs], 1);
            int pos2 = bbase_s[rs] + lp2;
            if (pos2 < SBCAP)
                gss[(size_t)rs * SBCAP + pos2] = (unsigned char)(s & 127);
        }
    }
}

// ---------------------------------------------------------------------------
// K2: per-bucket u8 histogram -> nrm, then scale bucket's 128 h2 rows in place
// ---------------------------------------------------------------------------
__global__ __launch_bounds__(256) void k_deg2(const int* __restrict__ qcnt2,
                                              const unsigned char* __restrict__ gss,
                                              unsigned short* __restrict__ h2) {
    __shared__ int hist[128];
    __shared__ float nrml[128];
    const int r = blockIdx.x;
    const int tid = threadIdx.x;
    if (tid < 128) hist[tid] = 0;
    __syncthreads();
    int cnt = qcnt2[2 * r + 1];
    if (cnt > SBCAP) cnt = SBCAP;
    const unsigned char* bp = gss + (size_t)r * SBCAP;
    for (int i = tid; i < cnt; i += 256)
        atomicAdd(&hist[bp[i]], 1);
    __syncthreads();
    if (tid < 128) {
        int dg = hist[tid];
        nrml[tid] = rsqrtf((float)(dg > 1 ? dg : 1));
    }
    __syncthreads();

    const int n0 = r << SB_SHIFT;
    for (int i = tid; i < 128 * 8; i += 256) {
        int row = i >> 3;
        int node = n0 + row;
        if (node < N_NODES) {
            float w = nrml[row];
            ushort4* p = reinterpret_cast<ushort4*>(&h2[(size_t)node * OUT_DIM]) + (i & 7);
            ushort4 v = *p;
            v.x = f2bf(bf2f(v.x) * w);
            v.y = f2bf(bf2f(v.y) * w);
            v.z = f2bf(bf2f(v.z) * w);
            v.w = f2bf(bf2f(v.w) * w);
            *p = v;
        }
    }
}

// ---------------------------------------------------------------------------
// K3: per-bucket sort + gather (bf16 h2 pre-scaled, unroll 4).
// ---------------------------------------------------------------------------
__global__ __launch_bounds__(512) void k_combo2(const int* __restrict__ qcnt2,
                                                const unsigned* __restrict__ gsb,
                                                const unsigned short* __restrict__ h2,
                                                const float* __restrict__ bias,
                                                float* __restrict__ out) {
    __shared__ unsigned pstage[SBCAP];   // 9472 B
    __shared__ int esl[SBCAP];           // 9472 B
    __shared__ int hist[128];
    __shared__ int pref[128];
    __shared__ int cur[128];

    const int r = blockIdx.x;
    const int tid = threadIdx.x;

    if (tid < 128) { hist[tid] = 0; cur[tid] = 0; }
    int cnt = qcnt2[2 * r];
    if (cnt > SBCAP) cnt = SBCAP;
    const unsigned* bp = gsb + (size_t)r * SBCAP;
    __syncthreads();

    for (int i = tid; i < cnt; i += 512) {
        unsigned pay = bp[i];
        pstage[i] = pay;
        atomicAdd(&hist[pay >> 17], 1);
    }
    __syncthreads();

    int v = 0;
    if (tid < 128) { v = hist[tid]; pref[tid] = v; }
    __syncthreads();
    #pragma unroll
    for (int off = 1; off < 128; off <<= 1) {
        int t = (tid < 128 && tid >= off) ? pref[tid - off] : 0;
        __syncthreads();
        if (tid < 128) pref[tid] += t;
        __syncthreads();
    }
    if (tid < 128) pref[tid] -= v;
    __syncthreads();

    for (int i = tid; i < cnt; i += 512) {
        unsigned pay = pstage[i];
        int l = (int)(pay >> 17);
        int lp = atomicAdd(&cur[l], 1);
        esl[pref[l] + lp] = (int)(pay & 0x1FFFF);
    }
    __syncthreads();

    const int q = tid & 7;
    const int nl = tid >> 3;
    const float4 bb = reinterpret_cast<const float4*>(bias)[q];
    #pragma unroll
    for (int sweep = 0; sweep < 2; ++sweep) {
        int l = sweep * 64 + nl;          // 0..127
        int st = pref[l];
        int deg = hist[l];
        float4 acc = make_float4(0.f, 0.f, 0.f, 0.f);
        int j = 0;
        for (; j + 4 <= deg; j += 4) {
            int s0 = esl[st + j + 0];
            int s1 = esl[st + j + 1];
            int s2 = esl[st + j + 2];
            int s3 = esl[st + j + 3];
            ushort4 a0 = *reinterpret_cast<const ushort4*>(&h2[(size_t)s0 * OUT_DIM + q * 4]);
            ushort4 a1 = *reinterpret_cast<const ushort4*>(&h2[(size_t)s1 * OUT_DIM + q * 4]);
            ushort4 a2 = *reinterpret_cast<const ushort4*>(&h2[(size_t)s2 * OUT_DIM + q * 4]);
            ushort4 a3 = *reinterpret_cast<const ushort4*>(&h2[(size_t)s3 * OUT_DIM + q * 4]);
            acc.x += (bf2f(a0.x) + bf2f(a1.x)) + (bf2f(a2.x) + bf2f(a3.x));
            acc.y += (bf2f(a0.y) + bf2f(a1.y)) + (bf2f(a2.y) + bf2f(a3.y));
            acc.z += (bf2f(a0.z) + bf2f(a1.z)) + (bf2f(a2.z) + bf2f(a3.z));
            acc.w += (bf2f(a0.w) + bf2f(a1.w)) + (bf2f(a2.w) + bf2f(a3.w));
        }
        for (; j < deg; ++j) {
            int s = esl[st + j];
            ushort4 a = *reinterpret_cast<const ushort4*>(&h2[(size_t)s * OUT_DIM + q * 4]);
            acc.x += bf2f(a.x); acc.y += bf2f(a.y);
            acc.z += bf2f(a.z); acc.w += bf2f(a.w);
        }
        int node = (r << SB_SHIFT) + l;
        if (node < N_NODES) {
            float nrm = rsqrtf((float)(deg > 1 ? deg : 1));
            float4 o = make_float4(acc.x * nrm + bb.x, acc.y * nrm + bb.y,
                                   acc.z * nrm + bb.z, acc.w * nrm + bb.w);
            reinterpret_cast<float4*>(out)[(size_t)node * 8 + q] = o;
        }
    }
}

// ---------------------------------------------------------------------------
extern "C" void kernel_launch(void* const* d_in, const int* in_sizes, int n_in,
                              void* d_out, int out_size, void* d_ws, size_t ws_size,
                              hipStream_t stream) {
    const float* x   = (const float*)d_in[0];
    const int*   src = (const int*)d_in[1];
    const int*   dst = (const int*)d_in[2];
    const float* W   = (const float*)d_in[3];
    const float* b   = (const float*)d_in[4];
    float* out = (float*)d_out;

    // ws bytes: qcnt u64[NSB] @0 | h2 bf16[N*32] @6272 |
    //           gsb u32[NSB*SBCAP] @6406272 | gss u8[NSB*SBCAP] @13813376
    unsigned long long* qcnt = (unsigned long long*)d_ws;
    int* qcnt2 = (int*)qcnt;
    unsigned short* h2 = (unsigned short*)((char*)d_ws + 6272);
    unsigned* gsb = (unsigned*)((char*)d_ws + 6406272);
    unsigned char* gss = (unsigned char*)((char*)d_ws + 13813376);

    hipMemsetAsync(qcnt, 0, NSB * sizeof(unsigned long long), stream);

    k_mega<<<NB1 + NGB, 512, 0, stream>>>(src, dst, qcnt, gsb, gss, x, W, h2);

    k_deg2<<<NSB, 256, 0, stream>>>(qcnt2, gss, h2);

    k_combo2<<<NSB, 512, 0, stream>>>(qcnt2, gsb, h2, b, out);
}

// Round 22
// 79.815 us; speedup vs baseline: 1.0396x; 1.0396x over previous
//
#include <hip/hip_runtime.h>

#define N_NODES 100000
#define N_EDGES 1600000
#define IN_DIM 256
#define OUT_DIM 32

#define SB_SHIFT 7                          // bucket = node >> 7 (128 nodes)
#define NSB ((N_NODES + 127) >> 7)          // 782
#define SBCAP 2368                          // mean 2046 + ~7 sigma
#define EBLK 2048                           // edges per part1 block
#define NB1 ((N_EDGES + EBLK - 1) / EBLK)   // 782
#define NGB ((N_NODES + 255) / 256)         // 391 gemm blocks

typedef __attribute__((ext_vector_type(8))) short short8;
typedef __attribute__((ext_vector_type(16))) float f32x16;

#define WT_STRIDE 264    // 256 + 8 pad (bf16 elems)

__device__ inline unsigned short f2bf(float f) {
    unsigned u = __float_as_uint(f);
    unsigned r = u + 0x7FFF + ((u >> 16) & 1);   // round-to-nearest-even
    return (unsigned short)(r >> 16);
}
__device__ inline float bf2f(unsigned short us) {
    return __uint_as_float((unsigned)us << 16);
}

// ---------------------------------------------------------------------------
// K1 mega (R22): R18 structure + forced load pipeline in the gemm branch.
// sched_barrier(0) after the prologue and after each refill pair pins load
// ISSUE order so the compiler cannot sink refills to their uses (R21 showed
// it collapses the rotation otherwise: VGPR stayed 32).
// part1 branch byte-identical to measured-best.
// ---------------------------------------------------------------------------
__global__ __launch_bounds__(512, 8) void k_mega(const int* __restrict__ src,
                                              const int* __restrict__ dst,
                                              unsigned long long* __restrict__ qcnt,
                                              unsigned* __restrict__ gsb,
                                              unsigned char* __restrict__ gss,
                                              const float* __restrict__ x,
                                              const float* __restrict__ W,
                                              unsigned short* __restrict__ h2) {
    __shared__ __align__(16) int smemI[6 * NSB + 2 * EBLK];   // 35152 B
    const int tid = threadIdx.x;
    const int bid = blockIdx.x;
    const int g = bid / 3;
    const int rem = bid - g * 3;

    if (rem == 0) {
        // ---------------- GEMM branch: rows [g*256, g*256+256) ----
        unsigned short* WT = (unsigned short*)smemI;   // 16896 B
        #pragma unroll
        for (int i = 0; i < 16; ++i) {
            int idx = tid + i * 512;        // k = idx>>5, c = idx&31
            WT[(idx & 31) * WT_STRIDE + (idx >> 5)] = f2bf(W[idx]);
        }
        __syncthreads();

        const int wv = tid >> 6;
        const int lane = tid & 63;
        const int col = lane & 31;
        const int hi = lane >> 5;

        const int row0 = g * 256 + wv * 32;
        int grow = row0 + col;
        int growc = grow < N_NODES ? grow : N_NODES - 1;
        const float4* xrow = reinterpret_cast<const float4*>(x + (size_t)growc * IN_DIM);

        f32x16 acc = {0.f,0.f,0.f,0.f,0.f,0.f,0.f,0.f,
                      0.f,0.f,0.f,0.f,0.f,0.f,0.f,0.f};

        // prologue: fill 4 slots (8 loads in flight), pin issue order
        float4 p0[4], p1[4];
        #pragma unroll
        for (int t = 0; t < 4; ++t) {
            p0[t] = xrow[t * 4 + hi * 2];
            p1[t] = xrow[t * 4 + hi * 2 + 1];
        }
        __builtin_amdgcn_sched_barrier(0);

        #pragma unroll
        for (int t = 0; t < 16; ++t) {
            const int sl = t & 3;
            float4 q0 = p0[sl];
            float4 q1 = p1[sl];
            if (t + 4 < 16) {               // refill slot 4 ahead
                p0[sl] = xrow[(t + 4) * 4 + hi * 2];
                p1[sl] = xrow[(t + 4) * 4 + hi * 2 + 1];
            }
            __builtin_amdgcn_sched_barrier(0);   // refill must ISSUE before this t's MFMA
            short8 a;
            a[0] = (short)f2bf(q0.x); a[1] = (short)f2bf(q0.y);
            a[2] = (short)f2bf(q0.z); a[3] = (short)f2bf(q0.w);
            a[4] = (short)f2bf(q1.x); a[5] = (short)f2bf(q1.y);
            a[6] = (short)f2bf(q1.z); a[7] = (short)f2bf(q1.w);
            short8 bfr = *reinterpret_cast<const short8*>(
                &WT[col * WT_STRIDE + t * 16 + hi * 8]);
            acc = __builtin_amdgcn_mfma_f32_32x32x16_bf16(a, bfr, acc, 0, 0, 0);
        }

        #pragma unroll
        for (int r = 0; r < 16; ++r) {
            int rowi = (r & 3) + 8 * (r >> 2) + 4 * hi;
            int go = row0 + rowi;
            if (go < N_NODES)
                h2[(size_t)go * OUT_DIM + col] = f2bf(acc[r]);   // norm deferred
        }
    } else {
        // ---------------- part1 branch: 782 buckets of 128 nodes ----
        const int pb = 2 * g + rem - 1;     // 0..781
        int* hist    = smemI;
        int* bbase   = smemI + NSB;
        int* cur     = smemI + 2 * NSB;
        int* hist_s  = smemI + 3 * NSB;
        int* bbase_s = smemI + 4 * NSB;
        int* cur_s   = smemI + 5 * NSB;
        int* es      = smemI + 6 * NSB;
        int* ed      = smemI + 6 * NSB + EBLK;

        const int e0 = pb * EBLK;
        const int n = min(EBLK, N_EDGES - e0);

        for (int i = tid; i < NSB; i += 512) {
            hist[i] = 0; cur[i] = 0; hist_s[i] = 0; cur_s[i] = 0;
        }
        __syncthreads();

        for (int i = tid; i < n; i += 512) {
            int s = src[e0 + i];
            int d = dst[e0 + i];
            es[i] = s; ed[i] = d;
            atomicAdd(&hist[d >> SB_SHIFT], 1);
            atomicAdd(&hist_s[s >> SB_SHIFT], 1);
        }
        __syncthreads();

        for (int i = tid; i < NSB; i += 512) {
            unsigned long long pack =
                ((unsigned long long)(unsigned)hist_s[i] << 32) | (unsigned)hist[i];
            unsigned long long old = atomicAdd(&qcnt[i], pack);
            bbase[i]   = (int)(old & 0xFFFFFFFFull);
            bbase_s[i] = (int)(old >> 32);
        }
        __syncthreads();

        for (int i = tid; i < n; i += 512) {
            int d = ed[i];
            int s = es[i];
            int r = d >> SB_SHIFT;
            int lp = atomicAdd(&cur[r], 1);
            int pos = bbase[r] + lp;
            if (pos < SBCAP)
                gsb[(size_t)r * SBCAP + pos] = ((unsigned)(d & 127) << 17) | (unsigned)s;
            int rs = s >> SB_SHIFT;
            int lp2 = atomicAdd(&cur_s[rs], 1);
            int pos2 = bbase_s[rs] + lp2;
            if (pos2 < SBCAP)
                gss[(size_t)rs * SBCAP + pos2] = (unsigned char)(s & 127);
        }
    }
}

// ---------------------------------------------------------------------------
// K2: per-bucket u8 histogram -> nrm, then scale bucket's 128 h2 rows in place
// ---------------------------------------------------------------------------
__global__ __launch_bounds__(256) void k_deg2(const int* __restrict__ qcnt2,
                                              const unsigned char* __restrict__ gss,
                                              unsigned short* __restrict__ h2) {
    __shared__ int hist[128];
    __shared__ float nrml[128];
    const int r = blockIdx.x;
    const int tid = threadIdx.x;
    if (tid < 128) hist[tid] = 0;
    __syncthreads();
    int cnt = qcnt2[2 * r + 1];
    if (cnt > SBCAP) cnt = SBCAP;
    const unsigned char* bp = gss + (size_t)r * SBCAP;
    for (int i = tid; i < cnt; i += 256)
        atomicAdd(&hist[bp[i]], 1);
    __syncthreads();
    if (tid < 128) {
        int dg = hist[tid];
        nrml[tid] = rsqrtf((float)(dg > 1 ? dg : 1));
    }
    __syncthreads();

    const int n0 = r << SB_SHIFT;
    for (int i = tid; i < 128 * 8; i += 256) {
        int row = i >> 3;
        int node = n0 + row;
        if (node < N_NODES) {
            float w = nrml[row];
            ushort4* p = reinterpret_cast<ushort4*>(&h2[(size_t)node * OUT_DIM]) + (i & 7);
            ushort4 v = *p;
            v.x = f2bf(bf2f(v.x) * w);
            v.y = f2bf(bf2f(v.y) * w);
            v.z = f2bf(bf2f(v.z) * w);
            v.w = f2bf(bf2f(v.w) * w);
            *p = v;
        }
    }
}

// ---------------------------------------------------------------------------
// K3: per-bucket sort + gather (bf16 h2 pre-scaled, unroll 4).
// ---------------------------------------------------------------------------
__global__ __launch_bounds__(512) void k_combo2(const int* __restrict__ qcnt2,
                                                const unsigned* __restrict__ gsb,
                                                const unsigned short* __restrict__ h2,
                                                const float* __restrict__ bias,
                                                float* __restrict__ out) {
    __shared__ unsigned pstage[SBCAP];   // 9472 B
    __shared__ int esl[SBCAP];           // 9472 B
    __shared__ int hist[128];
    __shared__ int pref[128];
    __shared__ int cur[128];

    const int r = blockIdx.x;
    const int tid = threadIdx.x;

    if (tid < 128) { hist[tid] = 0; cur[tid] = 0; }
    int cnt = qcnt2[2 * r];
    if (cnt > SBCAP) cnt = SBCAP;
    const unsigned* bp = gsb + (size_t)r * SBCAP;
    __syncthreads();

    for (int i = tid; i < cnt; i += 512) {
        unsigned pay = bp[i];
        pstage[i] = pay;
        atomicAdd(&hist[pay >> 17], 1);
    }
    __syncthreads();

    int v = 0;
    if (tid < 128) { v = hist[tid]; pref[tid] = v; }
    __syncthreads();
    #pragma unroll
    for (int off = 1; off < 128; off <<= 1) {
        int t = (tid < 128 && tid >= off) ? pref[tid - off] : 0;
        __syncthreads();
        if (tid < 128) pref[tid] += t;
        __syncthreads();
    }
    if (tid < 128) pref[tid] -= v;
    __syncthreads();

    for (int i = tid; i < cnt; i += 512) {
        unsigned pay = pstage[i];
        int l = (int)(pay >> 17);
        int lp = atomicAdd(&cur[l], 1);
        esl[pref[l] + lp] = (int)(pay & 0x1FFFF);
    }
    __syncthreads();

    const int q = tid & 7;
    const int nl = tid >> 3;
    const float4 bb = reinterpret_cast<const float4*>(bias)[q];
    #pragma unroll
    for (int sweep = 0; sweep < 2; ++sweep) {
        int l = sweep * 64 + nl;          // 0..127
        int st = pref[l];
        int deg = hist[l];
        float4 acc = make_float4(0.f, 0.f, 0.f, 0.f);
        int j = 0;
        for (; j + 4 <= deg; j += 4) {
            int s0 = esl[st + j + 0];
            int s1 = esl[st + j + 1];
            int s2 = esl[st + j + 2];
            int s3 = esl[st + j + 3];
            ushort4 a0 = *reinterpret_cast<const ushort4*>(&h2[(size_t)s0 * OUT_DIM + q * 4]);
            ushort4 a1 = *reinterpret_cast<const ushort4*>(&h2[(size_t)s1 * OUT_DIM + q * 4]);
            ushort4 a2 = *reinterpret_cast<const ushort4*>(&h2[(size_t)s2 * OUT_DIM + q * 4]);
            ushort4 a3 = *reinterpret_cast<const ushort4*>(&h2[(size_t)s3 * OUT_DIM + q * 4]);
            acc.x += (bf2f(a0.x) + bf2f(a1.x)) + (bf2f(a2.x) + bf2f(a3.x));
            acc.y += (bf2f(a0.y) + bf2f(a1.y)) + (bf2f(a2.y) + bf2f(a3.y));
            acc.z += (bf2f(a0.z) + bf2f(a1.z)) + (bf2f(a2.z) + bf2f(a3.z));
            acc.w += (bf2f(a0.w) + bf2f(a1.w)) + (bf2f(a2.w) + bf2f(a3.w));
        }
        for (; j < deg; ++j) {
            int s = esl[st + j];
            ushort4 a = *reinterpret_cast<const ushort4*>(&h2[(size_t)s * OUT_DIM + q * 4]);
            acc.x += bf2f(a.x); acc.y += bf2f(a.y);
            acc.z += bf2f(a.z); acc.w += bf2f(a.w);
        }
        int node = (r << SB_SHIFT) + l;
        if (node < N_NODES) {
            float nrm = rsqrtf((float)(deg > 1 ? deg : 1));
            float4 o = make_float4(acc.x * nrm + bb.x, acc.y * nrm + bb.y,
                                   acc.z * nrm + bb.z, acc.w * nrm + bb.w);
            reinterpret_cast<float4*>(out)[(size_t)node * 8 + q] = o;
        }
    }
}

// ---------------------------------------------------------------------------
extern "C" void kernel_launch(void* const* d_in, const int* in_sizes, int n_in,
                              void* d_out, int out_size, void* d_ws, size_t ws_size,
                              hipStream_t stream) {
    const float* x   = (const float*)d_in[0];
    const int*   src = (const int*)d_in[1];
    const int*   dst = (const int*)d_in[2];
    const float* W   = (const float*)d_in[3];
    const float* b   = (const float*)d_in[4];
    float* out = (float*)d_out;

    // ws bytes: qcnt u64[NSB] @0 | h2 bf16[N*32] @6272 |
    //           gsb u32[NSB*SBCAP] @6406272 | gss u8[NSB*SBCAP] @13813376
    unsigned long long* qcnt = (unsigned long long*)d_ws;
    int* qcnt2 = (int*)qcnt;
    unsigned short* h2 = (unsigned short*)((char*)d_ws + 6272);
    unsigned* gsb = (unsigned*)((char*)d_ws + 6406272);
    unsigned char* gss = (unsigned char*)((char*)d_ws + 13813376);

    hipMemsetAsync(qcnt, 0, NSB * sizeof(unsigned long long), stream);

    k_mega<<<NB1 + NGB, 512, 0, stream>>>(src, dst, qcnt, gsb, gss, x, W, h2);

    k_deg2<<<NSB, 256, 0, stream>>>(qcnt2, gss, h2);

    k_combo2<<<NSB, 512, 0, stream>>>(qcnt2, gsb, h2, b, out);
}